// Round 12
// baseline (610.643 us; speedup 1.0000x reference)
//
#include <hip/hip_runtime.h>
#include <hip/hip_cooperative_groups.h>
#include <math.h>

namespace cg = cooperative_groups;

#define EPS  1e-5f
#define EPS2 1e-10f
#define MAXN (1.0f - EPS)

using short8  = __attribute__((ext_vector_type(8))) short;
using floatx4 = __attribute__((ext_vector_type(4))) float;
using float2v = __attribute__((ext_vector_type(2))) float;

template <int CTRL>
static __device__ __forceinline__ float qperm(float x) {
  return __int_as_float(__builtin_amdgcn_update_dpp(
      __float_as_int(x), __float_as_int(x), CTRL, 0xF, 0xF, false));
}
#define QP_XOR1    0xB1
#define QP_XOR2    0x4E
#define QP_HALFMIR 0x141

#if __has_builtin(__builtin_elementwise_fma)
static __device__ __forceinline__ float2v fma2(float2v a, float2v b, float2v c) {
  return __builtin_elementwise_fma(a, b, c);
}
#else
static __device__ __forceinline__ float2v fma2(float2v a, float2v b, float2v c) {
  float2v r; r.x = fmaf(a.x, b.x, c.x); r.y = fmaf(a.y, b.y, c.y); return r;
}
#endif

static __device__ __forceinline__ int pack_hi2(float a, float b) {
  return (int)((__float_as_uint(a) >> 16) | (__float_as_uint(b) & 0xFFFF0000u));
}
static __device__ __forceinline__ float hi_of(float a) {
  return __uint_as_float(__float_as_uint(a) & 0xFFFF0000u);
}

static __device__ __forceinline__ float logmap_f(float ss) {
  const float r = sqrtf(fmaxf(ss, EPS2));
  float at;
  if (r >= MAXN) {
    at = 0.5f * logf((r * (2.0f - EPS) + EPS) / (EPS * (1.0f + r)));
  } else {
    at = 0.5f * logf((1.0f + r) / (1.0f - r));
  }
  return (1.0f + EPS) * at / r;
}

// ---- shared-memory overlays (one 37120 B buffer reused per phase) ----
struct SGemm { int Ahi[64][36]; int Alo[64][36]; int Whi[64][36]; int Wlo[64][36]; float f_lds[64]; };
struct SLog  { int Qhi[64][36]; int Qlo[64][36]; int Khi[64][36]; int Klo[64][36]; };
struct SScan { float v_lds[64 * 64]; float swyn[64 * 66]; float g[64]; };
struct SPost { float red[4][3]; };

// ---------- GEMM body: C = f[row]*(A @ W^T), 3-term bf16-split MFMA, fused rownorm ----------
static __device__ void gemm_body(const float* __restrict__ A, const float* __restrict__ W,
                                 float* __restrict__ C, int n0, int m0, SGemm* S) {
  const int t = threadIdx.x;
  const int row = t >> 2, c0 = (t & 3) * 16, ci = (t & 3) * 8;
  const int w = t >> 6, lane = t & 63;
  const int quad = lane >> 4, l16 = lane & 15;
  const int mw = (w & 1) * 32, nw = (w >> 1) * 32;
  floatx4 acc[2][2];
#pragma unroll
  for (int i = 0; i < 2; ++i)
#pragma unroll
    for (int j = 0; j < 2; ++j) acc[i][j] = (floatx4){0.f, 0.f, 0.f, 0.f};
  float ssq = 0.0f;

  for (int k0 = 0; k0 < 512; k0 += 64) {
    float4 av[4], wv[4];
#pragma unroll
    for (int i = 0; i < 4; ++i) {
      av[i] = *(const float4*)&A[(size_t)(n0 + row) * 512 + k0 + c0 + 4 * i];
      wv[i] = *(const float4*)&W[(size_t)(m0 + row) * 512 + k0 + c0 + 4 * i];
    }
    int pAh[8], pAl[8], pWh[8], pWl[8];
#pragma unroll
    for (int i = 0; i < 4; ++i) {
      ssq = fmaf(av[i].x, av[i].x, ssq); ssq = fmaf(av[i].y, av[i].y, ssq);
      ssq = fmaf(av[i].z, av[i].z, ssq); ssq = fmaf(av[i].w, av[i].w, ssq);
      pAh[2 * i]     = pack_hi2(av[i].x, av[i].y);
      pAh[2 * i + 1] = pack_hi2(av[i].z, av[i].w);
      pAl[2 * i]     = pack_hi2(av[i].x - hi_of(av[i].x), av[i].y - hi_of(av[i].y));
      pAl[2 * i + 1] = pack_hi2(av[i].z - hi_of(av[i].z), av[i].w - hi_of(av[i].w));
      pWh[2 * i]     = pack_hi2(wv[i].x, wv[i].y);
      pWh[2 * i + 1] = pack_hi2(wv[i].z, wv[i].w);
      pWl[2 * i]     = pack_hi2(wv[i].x - hi_of(wv[i].x), wv[i].y - hi_of(wv[i].y));
      pWl[2 * i + 1] = pack_hi2(wv[i].z - hi_of(wv[i].z), wv[i].w - hi_of(wv[i].w));
    }
    __syncthreads();
    *(int4*)&S->Ahi[row][ci]     = *(int4*)&pAh[0];
    *(int4*)&S->Ahi[row][ci + 4] = *(int4*)&pAh[4];
    *(int4*)&S->Alo[row][ci]     = *(int4*)&pAl[0];
    *(int4*)&S->Alo[row][ci + 4] = *(int4*)&pAl[4];
    *(int4*)&S->Whi[row][ci]     = *(int4*)&pWh[0];
    *(int4*)&S->Whi[row][ci + 4] = *(int4*)&pWh[4];
    *(int4*)&S->Wlo[row][ci]     = *(int4*)&pWl[0];
    *(int4*)&S->Wlo[row][ci + 4] = *(int4*)&pWl[4];
    __syncthreads();
#pragma unroll
    for (int kk = 0; kk < 64; kk += 32) {
      short8 ah[2], al[2], bh[2], bl[2];
#pragma unroll
      for (int i = 0; i < 2; ++i) {
        ah[i] = *(const short8*)&((const short*)S->Ahi[mw + i * 16 + l16])[kk + quad * 8];
        al[i] = *(const short8*)&((const short*)S->Alo[mw + i * 16 + l16])[kk + quad * 8];
        bh[i] = *(const short8*)&((const short*)S->Whi[nw + i * 16 + l16])[kk + quad * 8];
        bl[i] = *(const short8*)&((const short*)S->Wlo[nw + i * 16 + l16])[kk + quad * 8];
      }
#pragma unroll
      for (int i = 0; i < 2; ++i)
#pragma unroll
        for (int j = 0; j < 2; ++j) {
          acc[i][j] = __builtin_amdgcn_mfma_f32_16x16x32_bf16(ah[i], bh[j], acc[i][j], 0, 0, 0);
          acc[i][j] = __builtin_amdgcn_mfma_f32_16x16x32_bf16(ah[i], bl[j], acc[i][j], 0, 0, 0);
          acc[i][j] = __builtin_amdgcn_mfma_f32_16x16x32_bf16(al[i], bh[j], acc[i][j], 0, 0, 0);
        }
    }
  }
  ssq += qperm<QP_XOR1>(ssq);
  ssq += qperm<QP_XOR2>(ssq);
  if ((t & 3) == 0) S->f_lds[row] = logmap_f(ssq);
  __syncthreads();
#pragma unroll
  for (int i = 0; i < 2; ++i) {
    const int lrow_base = mw + i * 16 + quad * 4;
#pragma unroll
    for (int r = 0; r < 4; ++r) {
      const float fv = S->f_lds[lrow_base + r];
#pragma unroll
      for (int j = 0; j < 2; ++j)
        C[(size_t)(n0 + lrow_base + r) * 512 + m0 + nw + j * 16 + l16] = fv * acc[i][j][r];
    }
  }
}

// ---------- post body: expmap0 + mobius bias (+ per-head project/norms) ----------
static __device__ void post_body(const float* __restrict__ tin,
                                 const float* __restrict__ b0, const float* __restrict__ b1,
                                 const float* __restrict__ b2,
                                 float* __restrict__ o0, float* __restrict__ o1,
                                 float* __restrict__ o2,
                                 float* __restrict__ nrm0, float* __restrict__ nrm1,
                                 float* __restrict__ nrm2, float* __restrict__ rowsum_init,
                                 int nrow, int z, int final_mode, SPost* S) {
  const int t = threadIdx.x;
  const float* tv = tin + ((size_t)z * 2048 + nrow) * 512;
  const float* bias = (z == 0) ? b0 : ((z == 1) ? b1 : b2);
  const int e0 = 2 * t;
  const float2 tp = *(const float2*)&tv[e0];
  const float2 bp = *(const float2*)&bias[e0];
  float p_tt = tp.x * tp.x + tp.y * tp.y;
  float p_tb = tp.x * bp.x + tp.y * bp.y;
  float p_bb = bp.x * bp.x + bp.y * bp.y;
#pragma unroll
  for (int m = 32; m; m >>= 1) {
    p_tt += __shfl_xor(p_tt, m, 64);
    p_tb += __shfl_xor(p_tb, m, 64);
    p_bb += __shfl_xor(p_bb, m, 64);
  }
  const int lane = t & 63, w = t >> 6;
  if (lane == 0) { S->red[w][0] = p_tt; S->red[w][1] = p_tb; S->red[w][2] = p_bb; }
  __syncthreads();
  const float s_tt = S->red[0][0] + S->red[1][0] + S->red[2][0] + S->red[3][0];
  const float s_tb = S->red[0][1] + S->red[1][1] + S->red[2][1] + S->red[3][1];
  const float s_bb = S->red[0][2] + S->red[1][2] + S->red[2][2] + S->red[3][2];
  const float tn = sqrtf(fmaxf(s_tt, EPS2));
  const float th = tanhf(tn / (1.0f + EPS));
  const float g = th / tn;
  const float rnorm = th * (sqrtf(s_tt) / tn);
  const float sr = (rnorm >= MAXN) ? (MAXN / (rnorm + EPS)) : 1.0f;
  const float gr = g * sr;
  const float rn = (rnorm * sr) * (rnorm * sr);
  const float bnorm = sqrtf(fmaxf(s_bb, EPS2));
  const float sb = (bnorm >= MAXN) ? (MAXN / (bnorm + EPS)) : 1.0f;
  const float xy = gr * sb * s_tb;
  const float yn = (sb * sb) * s_bb;
  const float Af = 1.0f + 2.0f * xy + yn;
  const float Cf = 1.0f - rn;
  const float den = 1.0f + 2.0f * xy + rn * yn + EPS;
  const float id = 1.0f / den;
  const float on_raw = (Af * Af * rn + 2.0f * Af * Cf * xy + Cf * Cf * yn) * (id * id);
  const float no = sqrtf(fmaxf(on_raw, EPS2));
  const float so = (no >= MAXN) ? (MAXN / (no + EPS)) : 1.0f;
  const float ms = id * so;
  const float ca = gr * Af * ms;
  const float cb = sb * Cf * ms;
  const float v0 = ca * tp.x + cb * bp.x;
  const float v1 = ca * tp.y + cb * bp.y;
  if (final_mode) {
    float2 o; o.x = v0; o.y = v1;
    *(float2*)&o0[(size_t)nrow * 512 + e0] = o;
  } else {
    float hp = v0 * v0 + v1 * v1;
#pragma unroll
    for (int m = 16; m; m >>= 1) hp += __shfl_xor(hp, m, 64);
    const float hnr = sqrtf(fmaxf(hp, EPS2));
    float sh = 1.0f;
    if (z != 2) sh = (hnr >= MAXN) ? (MAXN / (hnr + EPS)) : 1.0f;
    float* outz = (z == 0) ? o0 : ((z == 1) ? o1 : o2);
    float* nz = (z == 0) ? nrm0 : ((z == 1) ? nrm1 : nrm2);
    const int b = nrow >> 9, s = nrow & 511, h = e0 >> 6, d = e0 & 63;
    float2 o; o.x = v0 * sh; o.y = v1 * sh;
    *(float2*)&outz[(((size_t)(b * 8 + h) * 512 + s) * 64 + d)] = o;
    if ((t & 31) == 0) nz[(size_t)(b * 8 + h) * 512 + s] = hp * sh * sh;
    if (z == 0 && t < 8) rowsum_init[((size_t)(nrow >> 9) * 8 + t) * 512 + (nrow & 511)] = 0.0f;
  }
}

// ---------- logits body: QK^T via bf16-split MFMA; r = exp(-dist) exactly ----------
static __device__ void logits_body(const float* __restrict__ Q, const float* __restrict__ K,
                                   const float* __restrict__ qn, const float* __restrict__ kn,
                                   float* __restrict__ attn, float* __restrict__ rowsum,
                                   int xb, int yb, int bh, SLog* S) {
  const int i0 = xb * 64;
  const int j0 = yb * 64;
  const float* Qb = Q + (size_t)bh * 512 * 64;
  const float* Kb = K + (size_t)bh * 512 * 64;
  const int t = threadIdx.x;
  const int row = t >> 2, c0 = (t & 3) * 16, ci = (t & 3) * 8;
  const int w = t >> 6, lane = t & 63;
  const int quad = lane >> 4, l16 = lane & 15;
  const int mw = (w & 1) * 32, nw = (w >> 1) * 32;
  float4 qv4[4], kv4[4];
#pragma unroll
  for (int i = 0; i < 4; ++i) {
    qv4[i] = *(const float4*)&Qb[(size_t)(i0 + row) * 64 + c0 + 4 * i];
    kv4[i] = *(const float4*)&Kb[(size_t)(j0 + row) * 64 + c0 + 4 * i];
  }
  int pQh[8], pQl[8], pKh[8], pKl[8];
#pragma unroll
  for (int i = 0; i < 4; ++i) {
    pQh[2 * i]     = pack_hi2(qv4[i].x, qv4[i].y);
    pQh[2 * i + 1] = pack_hi2(qv4[i].z, qv4[i].w);
    pQl[2 * i]     = pack_hi2(qv4[i].x - hi_of(qv4[i].x), qv4[i].y - hi_of(qv4[i].y));
    pQl[2 * i + 1] = pack_hi2(qv4[i].z - hi_of(qv4[i].z), qv4[i].w - hi_of(qv4[i].w));
    pKh[2 * i]     = pack_hi2(kv4[i].x, kv4[i].y);
    pKh[2 * i + 1] = pack_hi2(kv4[i].z, kv4[i].w);
    pKl[2 * i]     = pack_hi2(kv4[i].x - hi_of(kv4[i].x), kv4[i].y - hi_of(kv4[i].y));
    pKl[2 * i + 1] = pack_hi2(kv4[i].z - hi_of(kv4[i].z), kv4[i].w - hi_of(kv4[i].w));
  }
  __syncthreads();
  *(int4*)&S->Qhi[row][ci]     = *(int4*)&pQh[0];
  *(int4*)&S->Qhi[row][ci + 4] = *(int4*)&pQh[4];
  *(int4*)&S->Qlo[row][ci]     = *(int4*)&pQl[0];
  *(int4*)&S->Qlo[row][ci + 4] = *(int4*)&pQl[4];
  *(int4*)&S->Khi[row][ci]     = *(int4*)&pKh[0];
  *(int4*)&S->Khi[row][ci + 4] = *(int4*)&pKh[4];
  *(int4*)&S->Klo[row][ci]     = *(int4*)&pKl[0];
  *(int4*)&S->Klo[row][ci + 4] = *(int4*)&pKl[4];
  __syncthreads();
  floatx4 acc[2][2];
#pragma unroll
  for (int i = 0; i < 2; ++i)
#pragma unroll
    for (int j = 0; j < 2; ++j) acc[i][j] = (floatx4){0.f, 0.f, 0.f, 0.f};
#pragma unroll
  for (int kk = 0; kk < 64; kk += 32) {
    short8 ah[2], al[2], bhv[2], blv[2];
#pragma unroll
    for (int i = 0; i < 2; ++i) {
      ah[i]  = *(const short8*)&((const short*)S->Qhi[mw + i * 16 + l16])[kk + quad * 8];
      al[i]  = *(const short8*)&((const short*)S->Qlo[mw + i * 16 + l16])[kk + quad * 8];
      bhv[i] = *(const short8*)&((const short*)S->Khi[nw + i * 16 + l16])[kk + quad * 8];
      blv[i] = *(const short8*)&((const short*)S->Klo[nw + i * 16 + l16])[kk + quad * 8];
    }
#pragma unroll
    for (int i = 0; i < 2; ++i)
#pragma unroll
      for (int j = 0; j < 2; ++j) {
        acc[i][j] = __builtin_amdgcn_mfma_f32_16x16x32_bf16(ah[i], bhv[j], acc[i][j], 0, 0, 0);
        acc[i][j] = __builtin_amdgcn_mfma_f32_16x16x32_bf16(ah[i], blv[j], acc[i][j], 0, 0, 0);
        acc[i][j] = __builtin_amdgcn_mfma_f32_16x16x32_bf16(al[i], bhv[j], acc[i][j], 0, 0, 0);
      }
  }
#pragma unroll
  for (int i = 0; i < 2; ++i) {
    float rs_acc[4] = {0.f, 0.f, 0.f, 0.f};
#pragma unroll
    for (int r = 0; r < 4; ++r) {
      const int grow = i0 + mw + i * 16 + quad * 4 + r;
      const float qni = qn[(size_t)bh * 512 + grow];
      const float rq = 1.0f - qni;
#pragma unroll
      for (int j = 0; j < 2; ++j) {
        const int gcol = j0 + nw + j * 16 + l16;
        const float knj = kn[(size_t)bh * 512 + gcol];
        const float num = fmaxf(qni + knj - 2.0f * acc[i][j][r], 0.0f);
        const float den = fmaxf(rq * (1.0f - knj), EPS);
        const float wv = fmaf(2.0f * num, __builtin_amdgcn_rcpf(den), EPS);
        const float s_ = 1.0f + wv + sqrtf(wv * (wv + 2.0f));
        const float rr = __builtin_amdgcn_rcpf(s_);
        rs_acc[r] += rr;
        attn[((size_t)bh * 512 + grow) * 512 + gcol] = rr;
      }
    }
#pragma unroll
    for (int r = 0; r < 4; ++r) {
      float v = rs_acc[r];
      v += __shfl_xor(v, 1, 64); v += __shfl_xor(v, 2, 64);
      v += __shfl_xor(v, 4, 64); v += __shfl_xor(v, 8, 64);
      if (l16 == 0)
        atomicAdd(&rowsum[(size_t)bh * 512 + i0 + mw + i * 16 + quad * 4 + r], v);
    }
  }
}

// ---------- scan body: 8 lanes/row + one-step dot lookahead (v11) ----------
static __device__ void scan_body(const float* __restrict__ V, const float* __restrict__ vn,
                                 const float* __restrict__ rw, const float* __restrict__ rowsum,
                                 float* __restrict__ att, int blk, SScan* S) {
  const int bh = blk >> 4;
  const int i0 = (blk & 15) * 32;
  const int t = threadIdx.x;
  const int lane = t & 63, w = t >> 6;
  const int row_blk = w * 8 + (lane >> 3);
  const int sub = lane & 7;
  const int d0 = sub * 8;
  const float* Vb = V + (size_t)bh * 512 * 64;
  const float* vnb = vn + (size_t)bh * 512;
  const float* arow = rw + ((size_t)bh * 512 + i0 + row_blk) * 512;
  const float inv_s = __builtin_amdgcn_rcpf(rowsum[(size_t)bh * 512 + i0 + row_blk]);

  float2v wsv[4];
#pragma unroll
  for (int k = 0; k < 4; ++k) wsv[k] = (float2v){0.f, 0.f};
  float xn = 0.0f;

  for (int jc = 0; jc < 512; jc += 64) {
#pragma unroll
    for (int it = 0; it < 4; ++it) {
      const int idx4 = it * 256 + t;
      *(float4*)&S->v_lds[idx4 * 4] = *(const float4*)&Vb[(size_t)jc * 64 + idx4 * 4];
    }
    const float4 a0 = *(const float4*)&arow[jc + sub * 8];
    const float4 a1 = *(const float4*)&arow[jc + sub * 8 + 4];
    const float4 n0 = *(const float4*)&vnb[jc + sub * 8];
    const float4 n1 = *(const float4*)&vnb[jc + sub * 8 + 4];
    const float wq[8] = {a0.x, a0.y, a0.z, a0.w, a1.x, a1.y, a1.z, a1.w};
    const float nq[8] = {n0.x, n0.y, n0.z, n0.w, n1.x, n1.y, n1.z, n1.w};
#pragma unroll
    for (int e = 0; e < 8; ++e) {
      const float wgt = wq[e] * inv_s;
      float2 p; p.x = wgt; p.y = (wgt * wgt) * nq[e];
      *(float2*)&S->swyn[(sub * 8 + e) * 66 + row_blk * 2] = p;
    }
    __syncthreads();

    {
      const int jg = row_blk * 2;
      const float4 va0 = *(const float4*)&S->v_lds[jg * 64 + d0];
      const float4 va1 = *(const float4*)&S->v_lds[jg * 64 + d0 + 4];
      const float4 vb0 = *(const float4*)&S->v_lds[(jg + 1) * 64 + d0];
      const float4 vb1 = *(const float4*)&S->v_lds[(jg + 1) * 64 + d0 + 4];
      const float4 vc0 = *(const float4*)&S->v_lds[((jg + 2) & 63) * 64 + d0];
      const float4 vc1 = *(const float4*)&S->v_lds[((jg + 2) & 63) * 64 + d0 + 4];
      float p0 = va0.x * vb0.x + va0.y * vb0.y + va0.z * vb0.z + va0.w * vb0.w +
                 va1.x * vb1.x + va1.y * vb1.y + va1.z * vb1.z + va1.w * vb1.w;
      float p1 = vb0.x * vc0.x + vb0.y * vc0.y + vb0.z * vc0.z + vb0.w * vc0.w +
                 vb1.x * vc1.x + vb1.y * vc1.y + vb1.z * vc1.z + vb1.w * vc1.w;
      p0 += qperm<QP_XOR1>(p0); p0 += qperm<QP_XOR2>(p0); p0 += qperm<QP_HALFMIR>(p0);
      p1 += qperm<QP_XOR1>(p1); p1 += qperm<QP_XOR2>(p1); p1 += qperm<QP_HALFMIR>(p1);
      if (sub == 0) { S->g[jg] = p0; S->g[jg + 1] = p1; }
    }
    float2v vcur[4];
    {
      const float4 c0v = *(const float4*)&S->v_lds[d0];
      const float4 c1v = *(const float4*)&S->v_lds[d0 + 4];
      vcur[0] = (float2v){c0v.x, c0v.y}; vcur[1] = (float2v){c0v.z, c0v.w};
      vcur[2] = (float2v){c1v.x, c1v.y}; vcur[3] = (float2v){c1v.z, c1v.w};
    }
    float2v dd = wsv[0] * vcur[0];
    dd = fma2(wsv[1], vcur[1], dd);
    dd = fma2(wsv[2], vcur[2], dd);
    dd = fma2(wsv[3], vcur[3], dd);
    float D = dd.x + dd.y;
    D += qperm<QP_XOR1>(D); D += qperm<QP_XOR2>(D); D += qperm<QP_HALFMIR>(D);
    __syncthreads();

#pragma unroll
    for (int j = 0; j < 64; ++j) {
      const float2 sy2 = *(const float2*)&S->swyn[j * 66 + row_blk * 2];
      const float sw = sy2.x, yn = sy2.y;
      const float xnyn1 = fmaf(xn, yn, 1.0f + EPS);
      const float sxy   = xn + yn;
      const float ynp1  = 1.0f + yn;
      const float Cfsw  = (1.0f - xn) * sw;
      float2v vnx[4];
      float E = 0.0f;
      if (j < 63) {
        const float4 nx0 = *(const float4*)&S->v_lds[(j + 1) * 64 + d0];
        const float4 nx1 = *(const float4*)&S->v_lds[(j + 1) * 64 + d0 + 4];
        vnx[0] = (float2v){nx0.x, nx0.y}; vnx[1] = (float2v){nx0.z, nx0.w};
        vnx[2] = (float2v){nx1.x, nx1.y}; vnx[3] = (float2v){nx1.z, nx1.w};
        float2v ee = wsv[0] * vnx[0];
        ee = fma2(wsv[1], vnx[1], ee);
        ee = fma2(wsv[2], vnx[2], ee);
        ee = fma2(wsv[3], vnx[3], ee);
        E = ee.x + ee.y;
        E += qperm<QP_XOR1>(E); E += qperm<QP_XOR2>(E); E += qperm<QP_HALFMIR>(E);
      }
      const float xy  = sw * D;
      const float den = fmaf(2.0f, xy, xnyn1);
      const float s2  = fmaf(2.0f, xy, sxy);
      const float Af  = fmaf(2.0f, xy, ynp1);
      const float id  = __builtin_amdgcn_rcpf(den);
      const float dn  = den - EPS;
      const float am  = Af * id;
      const float cm  = Cfsw * id;
      xn = (s2 * id) * (dn * id);
      const float2v amv = {am, am};
      const float2v cmv = {cm, cm};
      wsv[0] = fma2(amv, wsv[0], cmv * vcur[0]);
      wsv[1] = fma2(amv, wsv[1], cmv * vcur[1]);
      wsv[2] = fma2(amv, wsv[2], cmv * vcur[2]);
      wsv[3] = fma2(amv, wsv[3], cmv * vcur[3]);
      if (j < 63) {
        D = fmaf(am, E, cm * S->g[j]);
        vcur[0] = vnx[0]; vcur[1] = vnx[1]; vcur[2] = vnx[2]; vcur[3] = vnx[3];
      }
    }
    __syncthreads();
  }
  const int b = bh >> 3, h = bh & 7;
  float* o = att + (((size_t)b * 512 + i0 + row_blk) * 512 + h * 64 + d0);
  float4 s0; s0.x = wsv[0].x; s0.y = wsv[0].y; s0.z = wsv[1].x; s0.w = wsv[1].y;
  float4 s1; s1.x = wsv[2].x; s1.y = wsv[2].y; s1.z = wsv[3].x; s1.w = wsv[3].y;
  *(float4*)&o[0] = s0;
  *(float4*)&o[4] = s1;
}

// ---------- the mega kernel: all phases, one cooperative launch ----------
__global__ __launch_bounds__(256, 2) void k_mega(
    const float* query, const float* key_, const float* value,
    const float* Wq, const float* bq, const float* Wk, const float* bk,
    const float* Wv, const float* bv, const float* Wo, const float* bo,
    float* Qb, float* Kb, float* Vb, float* qn, float* kn, float* vnrm,
    float* rowsum, float* rw, float* t3, float* att, float* to_, float* out) {
  __shared__ __align__(16) char smem_raw[sizeof(SGemm)];
  cg::grid_group grid = cg::this_grid();
  const int bid = blockIdx.x;   // 512 blocks

  // Phase 1: QKV hyperbolic linear GEMMs (768 vblocks: 32 M x 8 N x 3 z)
  for (int v = bid; v < 768; v += 512) {
    const int z = v >> 8, rem = v & 255;
    const float* A = (z == 0) ? query : ((z == 1) ? key_ : value);
    const float* W = (z == 0) ? Wq : ((z == 1) ? Wk : Wv);
    gemm_body(A, W, t3 + (size_t)z * (2048 * 512), (rem & 31) * 64, (rem >> 5) * 64,
              (SGemm*)smem_raw);
    __syncthreads();
  }
  grid.sync();

  // Phase 2: expmap0+bias+per-head projection (6144 vblocks) + rowsum zero-init
  for (int v = bid; v < 6144; v += 512) {
    post_body(t3, bq, bk, bv, Qb, Kb, Vb, qn, kn, vnrm, rowsum,
              v & 2047, v >> 11, 0, (SPost*)smem_raw);
    __syncthreads();
  }
  grid.sync();

  // Phase 3: distance logits -> unnormalized weights + rowsums (2048 vblocks)
  for (int v = bid; v < 2048; v += 512) {
    logits_body(Qb, Kb, qn, kn, rw, rowsum, v & 7, (v >> 3) & 7, v >> 6,
                (SLog*)smem_raw);
    __syncthreads();
  }
  __threadfence();
  grid.sync();

  // Phase 4: sequential mobius scan (512 vblocks, 1:1)
  scan_body(Vb, vnrm, rw, rowsum, att, bid, (SScan*)smem_raw);
  grid.sync();

  // Phase 5: output hyperbolic linear GEMM (256 vblocks: 32 M x 8 N)
  for (int v = bid; v < 256; v += 512) {
    gemm_body(att, Wo, to_, (v & 31) * 64, (v >> 5) * 64, (SGemm*)smem_raw);
    __syncthreads();
  }
  grid.sync();

  // Phase 6: final expmap0+bias (2048 vblocks)
  for (int v = bid; v < 2048; v += 512) {
    post_body(to_, bo, bo, bo, out, nullptr, nullptr, nullptr, nullptr, nullptr,
              nullptr, v, 0, 1, (SPost*)smem_raw);
    __syncthreads();
  }
}

extern "C" void kernel_launch(void* const* d_in, const int* in_sizes, int n_in,
                              void* d_out, int out_size, void* d_ws, size_t ws_size,
                              hipStream_t stream) {
  const float* query = (const float*)d_in[0];
  const float* key_  = (const float*)d_in[1];
  const float* value = (const float*)d_in[2];
  const float* Wq = (const float*)d_in[3];
  const float* bq = (const float*)d_in[4];
  const float* Wk = (const float*)d_in[5];
  const float* bk = (const float*)d_in[6];
  const float* Wv = (const float*)d_in[7];
  const float* bv = (const float*)d_in[8];
  const float* Wo = (const float*)d_in[9];
  const float* bo = (const float*)d_in[10];
  float* ws = (float*)d_ws;
  const size_t M = 1u << 20;            // 1M floats
  float* Qb     = ws;                   // [32,512,64]
  float* Kb     = ws + 1 * M;
  float* Vb     = ws + 2 * M;
  float* qn     = ws + 3 * M;           // [32,512]
  float* kn     = qn + 16384;
  float* vn     = kn + 16384;
  float* rowsum = vn + 16384;           // [32,512]
  float* rw     = ws + 4 * M;           // [32,512,512]
  float* t3     = ws + 12 * M;          // 3x [2048,512]
  float* att    = ws + 15 * M;          // [2048,512]
  float* to_    = ws + 16 * M;          // [2048,512]
  float* out    = (float*)d_out;

  void* args[] = {
    (void*)&query, (void*)&key_, (void*)&value,
    (void*)&Wq, (void*)&bq, (void*)&Wk, (void*)&bk,
    (void*)&Wv, (void*)&bv, (void*)&Wo, (void*)&bo,
    (void*)&Qb, (void*)&Kb, (void*)&Vb, (void*)&qn, (void*)&kn, (void*)&vn,
    (void*)&rowsum, (void*)&rw, (void*)&t3, (void*)&att, (void*)&to_, (void*)&out,
  };
  hipLaunchCooperativeKernel((const void*)k_mega, dim3(512), dim3(256), args, 0, stream);
}

// Round 13
// 232.948 us; speedup vs baseline: 2.6214x; 2.6214x over previous
//
#include <hip/hip_runtime.h>
#include <math.h>

#define EPS  1e-5f
#define EPS2 1e-10f
#define MAXN (1.0f - EPS)

using short8  = __attribute__((ext_vector_type(8))) short;
using floatx4 = __attribute__((ext_vector_type(4))) float;
using float2v = __attribute__((ext_vector_type(2))) float;

// DPP cross-lane: pure VALU, never touches the LDS pipe
template <int CTRL>
static __device__ __forceinline__ float qperm(float x) {
  return __int_as_float(__builtin_amdgcn_update_dpp(
      __float_as_int(x), __float_as_int(x), CTRL, 0xF, 0xF, false));
}
#define QP_XOR1    0xB1   // quad_perm [1,0,3,2]
#define QP_XOR2    0x4E   // quad_perm [2,3,0,1]
#define QP_HALFMIR 0x141  // row_half_mirror: lane -> lane^7 within 8

#if __has_builtin(__builtin_elementwise_fma)
static __device__ __forceinline__ float2v fma2(float2v a, float2v b, float2v c) {
  return __builtin_elementwise_fma(a, b, c);
}
#else
static __device__ __forceinline__ float2v fma2(float2v a, float2v b, float2v c) {
  float2v r; r.x = fmaf(a.x, b.x, c.x); r.y = fmaf(a.y, b.y, c.y); return r;
}
#endif

// truncation bf16 split, pair-packed
static __device__ __forceinline__ int pack_hi2(float a, float b) {
  return (int)((__float_as_uint(a) >> 16) | (__float_as_uint(b) & 0xFFFF0000u));
}
static __device__ __forceinline__ float hi_of(float a) {
  return __uint_as_float(__float_as_uint(a) & 0xFFFF0000u);
}

static __device__ __forceinline__ float logmap_f(float ss) {
  const float r = sqrtf(fmaxf(ss, EPS2));
  float at;
  if (r >= MAXN) {
    at = 0.5f * logf((r * (2.0f - EPS) + EPS) / (EPS * (1.0f + r)));
  } else {
    at = 0.5f * logf((1.0f + r) / (1.0f - r));
  }
  return (1.0f + EPS) * at / r;
}

// ---------- K2: C = f[row]*(A @ W^T) via 3-term bf16-split MFMA ----------
__global__ __launch_bounds__(256) void k_gemm_mfma(
    const float* __restrict__ A0, const float* __restrict__ A1, const float* __restrict__ A2,
    const float* __restrict__ W0, const float* __restrict__ W1, const float* __restrict__ W2,
    float* __restrict__ Cbase) {
  const int z = blockIdx.z;
  const float* A = (z == 0) ? A0 : ((z == 1) ? A1 : A2);
  const float* W = (z == 0) ? W0 : ((z == 1) ? W1 : W2);
  float* C = Cbase + (size_t)z * (2048 * 512);
  __shared__ int Ahi[64][36], Alo[64][36], Whi[64][36], Wlo[64][36];
  __shared__ float f_lds[64];
  const int t = threadIdx.x;
  const int n0 = blockIdx.x * 64;
  const int m0 = blockIdx.y * 64;
  const int row = t >> 2, c0 = (t & 3) * 16, ci = (t & 3) * 8;
  const int w = t >> 6, lane = t & 63;
  const int quad = lane >> 4, l16 = lane & 15;
  const int mw = (w & 1) * 32, nw = (w >> 1) * 32;
  floatx4 acc[2][2];
#pragma unroll
  for (int i = 0; i < 2; ++i)
#pragma unroll
    for (int j = 0; j < 2; ++j) acc[i][j] = (floatx4){0.f, 0.f, 0.f, 0.f};
  float ssq = 0.0f;

  for (int k0 = 0; k0 < 512; k0 += 64) {
    float4 av[4], wv[4];
#pragma unroll
    for (int i = 0; i < 4; ++i) {
      av[i] = *(const float4*)&A[(size_t)(n0 + row) * 512 + k0 + c0 + 4 * i];
      wv[i] = *(const float4*)&W[(size_t)(m0 + row) * 512 + k0 + c0 + 4 * i];
    }
    int pAh[8], pAl[8], pWh[8], pWl[8];
#pragma unroll
    for (int i = 0; i < 4; ++i) {
      ssq = fmaf(av[i].x, av[i].x, ssq); ssq = fmaf(av[i].y, av[i].y, ssq);
      ssq = fmaf(av[i].z, av[i].z, ssq); ssq = fmaf(av[i].w, av[i].w, ssq);
      pAh[2 * i]     = pack_hi2(av[i].x, av[i].y);
      pAh[2 * i + 1] = pack_hi2(av[i].z, av[i].w);
      pAl[2 * i]     = pack_hi2(av[i].x - hi_of(av[i].x), av[i].y - hi_of(av[i].y));
      pAl[2 * i + 1] = pack_hi2(av[i].z - hi_of(av[i].z), av[i].w - hi_of(av[i].w));
      pWh[2 * i]     = pack_hi2(wv[i].x, wv[i].y);
      pWh[2 * i + 1] = pack_hi2(wv[i].z, wv[i].w);
      pWl[2 * i]     = pack_hi2(wv[i].x - hi_of(wv[i].x), wv[i].y - hi_of(wv[i].y));
      pWl[2 * i + 1] = pack_hi2(wv[i].z - hi_of(wv[i].z), wv[i].w - hi_of(wv[i].w));
    }
    __syncthreads();
    *(int4*)&Ahi[row][ci]     = *(int4*)&pAh[0];
    *(int4*)&Ahi[row][ci + 4] = *(int4*)&pAh[4];
    *(int4*)&Alo[row][ci]     = *(int4*)&pAl[0];
    *(int4*)&Alo[row][ci + 4] = *(int4*)&pAl[4];
    *(int4*)&Whi[row][ci]     = *(int4*)&pWh[0];
    *(int4*)&Whi[row][ci + 4] = *(int4*)&pWh[4];
    *(int4*)&Wlo[row][ci]     = *(int4*)&pWl[0];
    *(int4*)&Wlo[row][ci + 4] = *(int4*)&pWl[4];
    __syncthreads();
#pragma unroll
    for (int kk = 0; kk < 64; kk += 32) {
      short8 ah[2], al[2], bh[2], bl[2];
#pragma unroll
      for (int i = 0; i < 2; ++i) {
        ah[i] = *(const short8*)&((const short*)Ahi[mw + i * 16 + l16])[kk + quad * 8];
        al[i] = *(const short8*)&((const short*)Alo[mw + i * 16 + l16])[kk + quad * 8];
        bh[i] = *(const short8*)&((const short*)Whi[nw + i * 16 + l16])[kk + quad * 8];
        bl[i] = *(const short8*)&((const short*)Wlo[nw + i * 16 + l16])[kk + quad * 8];
      }
#pragma unroll
      for (int i = 0; i < 2; ++i)
#pragma unroll
        for (int j = 0; j < 2; ++j) {
          acc[i][j] = __builtin_amdgcn_mfma_f32_16x16x32_bf16(ah[i], bh[j], acc[i][j], 0, 0, 0);
          acc[i][j] = __builtin_amdgcn_mfma_f32_16x16x32_bf16(ah[i], bl[j], acc[i][j], 0, 0, 0);
          acc[i][j] = __builtin_amdgcn_mfma_f32_16x16x32_bf16(al[i], bh[j], acc[i][j], 0, 0, 0);
        }
    }
  }
  ssq += qperm<QP_XOR1>(ssq);
  ssq += qperm<QP_XOR2>(ssq);
  if ((t & 3) == 0) f_lds[row] = logmap_f(ssq);
  __syncthreads();
#pragma unroll
  for (int i = 0; i < 2; ++i) {
    const int lrow_base = mw + i * 16 + quad * 4;
#pragma unroll
    for (int r = 0; r < 4; ++r) {
      const float fv = f_lds[lrow_base + r];
#pragma unroll
      for (int j = 0; j < 2; ++j)
        C[(size_t)(n0 + lrow_base + r) * 512 + m0 + nw + j * 16 + l16] = fv * acc[i][j][r];
    }
  }
}

// ---------- K3 v2: ONE ROW PER WAVE; no LDS, no block barriers ----------
__global__ __launch_bounds__(256) void k_post(const float* __restrict__ tin,
                                              const float* __restrict__ b0,
                                              const float* __restrict__ b1,
                                              const float* __restrict__ b2,
                                              float* __restrict__ o0, float* __restrict__ o1,
                                              float* __restrict__ o2,
                                              float* __restrict__ nrm0, float* __restrict__ nrm1,
                                              float* __restrict__ nrm2,
                                              float* __restrict__ rowsum_init, int final_mode) {
  const int t = threadIdx.x;
  const int wv = t >> 6, lane = t & 63;
  const int nrow = blockIdx.x * 4 + wv;    // 4 rows/block
  const int z = blockIdx.y;
  const float* tv = tin + ((size_t)z * 2048 + nrow) * 512;
  const float* bias = (z == 0) ? b0 : ((z == 1) ? b1 : b2);
  const int e0 = lane * 8;
  const float4 tp0 = *(const float4*)&tv[e0];
  const float4 tp1 = *(const float4*)&tv[e0 + 4];
  const float4 bp0 = *(const float4*)&bias[e0];
  const float4 bp1 = *(const float4*)&bias[e0 + 4];
  const float tpv[8] = {tp0.x, tp0.y, tp0.z, tp0.w, tp1.x, tp1.y, tp1.z, tp1.w};
  const float bpv[8] = {bp0.x, bp0.y, bp0.z, bp0.w, bp1.x, bp1.y, bp1.z, bp1.w};
  float p_tt = 0.f, p_tb = 0.f, p_bb = 0.f;
#pragma unroll
  for (int e = 0; e < 8; ++e) {
    p_tt = fmaf(tpv[e], tpv[e], p_tt);
    p_tb = fmaf(tpv[e], bpv[e], p_tb);
    p_bb = fmaf(bpv[e], bpv[e], p_bb);
  }
#pragma unroll
  for (int m = 32; m; m >>= 1) {
    p_tt += __shfl_xor(p_tt, m, 64);
    p_tb += __shfl_xor(p_tb, m, 64);
    p_bb += __shfl_xor(p_bb, m, 64);
  }
  const float s_tt = p_tt, s_tb = p_tb, s_bb = p_bb;
  const float tn = sqrtf(fmaxf(s_tt, EPS2));
  const float th = tanhf(tn / (1.0f + EPS));
  const float g = th / tn;
  const float rnorm = th * (sqrtf(s_tt) / tn);
  const float sr = (rnorm >= MAXN) ? (MAXN / (rnorm + EPS)) : 1.0f;
  const float gr = g * sr;
  const float rn = (rnorm * sr) * (rnorm * sr);
  const float bnorm = sqrtf(fmaxf(s_bb, EPS2));
  const float sb = (bnorm >= MAXN) ? (MAXN / (bnorm + EPS)) : 1.0f;
  const float xy = gr * sb * s_tb;
  const float yn = (sb * sb) * s_bb;
  const float Af = 1.0f + 2.0f * xy + yn;
  const float Cf = 1.0f - rn;
  const float den = 1.0f + 2.0f * xy + rn * yn + EPS;
  const float id = 1.0f / den;
  const float on_raw = (Af * Af * rn + 2.0f * Af * Cf * xy + Cf * Cf * yn) * (id * id);
  const float no = sqrtf(fmaxf(on_raw, EPS2));
  const float so = (no >= MAXN) ? (MAXN / (no + EPS)) : 1.0f;
  const float ms = id * so;
  const float ca = gr * Af * ms;
  const float cb = sb * Cf * ms;
  float v[8];
#pragma unroll
  for (int e = 0; e < 8; ++e) v[e] = ca * tpv[e] + cb * bpv[e];
  if (final_mode) {
    float4 oa; oa.x = v[0]; oa.y = v[1]; oa.z = v[2]; oa.w = v[3];
    float4 ob; ob.x = v[4]; ob.y = v[5]; ob.z = v[6]; ob.w = v[7];
    *(float4*)&o0[(size_t)nrow * 512 + e0] = oa;
    *(float4*)&o0[(size_t)nrow * 512 + e0 + 4] = ob;
    return;
  }
  // per-head (64-elem = 8-lane group) norm via 3 shuffles
  float hp = 0.f;
#pragma unroll
  for (int e = 0; e < 8; ++e) hp = fmaf(v[e], v[e], hp);
  hp += __shfl_xor(hp, 1, 64);
  hp += __shfl_xor(hp, 2, 64);
  hp += __shfl_xor(hp, 4, 64);
  const float hnr = sqrtf(fmaxf(hp, EPS2));
  float sh = 1.0f;
  if (z != 2) sh = (hnr >= MAXN) ? (MAXN / (hnr + EPS)) : 1.0f;
  float* outz = (z == 0) ? o0 : ((z == 1) ? o1 : o2);
  float* nz = (z == 0) ? nrm0 : ((z == 1) ? nrm1 : nrm2);
  const int b = nrow >> 9, s = nrow & 511, h = lane >> 3, d = (lane & 7) * 8;
  float4 oa; oa.x = v[0] * sh; oa.y = v[1] * sh; oa.z = v[2] * sh; oa.w = v[3] * sh;
  float4 ob; ob.x = v[4] * sh; ob.y = v[5] * sh; ob.z = v[6] * sh; ob.w = v[7] * sh;
  float* op = &outz[(((size_t)(b * 8 + h) * 512 + s) * 64 + d)];
  *(float4*)&op[0] = oa;
  *(float4*)&op[4] = ob;
  if ((lane & 7) == 0) nz[(size_t)(b * 8 + h) * 512 + s] = hp * sh * sh;
  if (z == 0 && lane < 8) rowsum_init[((size_t)b * 8 + lane) * 512 + s] = 0.0f;
}

// ---------- K4: QK^T via bf16-split MFMA; r = exp(-dist) = rcp(z+sqrt(z^2-1)) ----------
__global__ __launch_bounds__(256) void k_logits(const float* __restrict__ Q,
                                                const float* __restrict__ K,
                                                const float* __restrict__ qn,
                                                const float* __restrict__ kn,
                                                float* __restrict__ attn,
                                                float* __restrict__ rowsum) {
  const int bh = blockIdx.z;
  const int i0 = blockIdx.x * 64;
  const int j0 = blockIdx.y * 64;
  const float* Qb = Q + (size_t)bh * 512 * 64;
  const float* Kb = K + (size_t)bh * 512 * 64;
  __shared__ int Qhi[64][36], Qlo[64][36], Khi[64][36], Klo[64][36];
  const int t = threadIdx.x;
  const int row = t >> 2, c0 = (t & 3) * 16, ci = (t & 3) * 8;
  const int w = t >> 6, lane = t & 63;
  const int quad = lane >> 4, l16 = lane & 15;
  const int mw = (w & 1) * 32, nw = (w >> 1) * 32;
  float4 qv4[4], kv4[4];
#pragma unroll
  for (int i = 0; i < 4; ++i) {
    qv4[i] = *(const float4*)&Qb[(size_t)(i0 + row) * 64 + c0 + 4 * i];
    kv4[i] = *(const float4*)&Kb[(size_t)(j0 + row) * 64 + c0 + 4 * i];
  }
  int pQh[8], pQl[8], pKh[8], pKl[8];
#pragma unroll
  for (int i = 0; i < 4; ++i) {
    pQh[2 * i]     = pack_hi2(qv4[i].x, qv4[i].y);
    pQh[2 * i + 1] = pack_hi2(qv4[i].z, qv4[i].w);
    pQl[2 * i]     = pack_hi2(qv4[i].x - hi_of(qv4[i].x), qv4[i].y - hi_of(qv4[i].y));
    pQl[2 * i + 1] = pack_hi2(qv4[i].z - hi_of(qv4[i].z), qv4[i].w - hi_of(qv4[i].w));
    pKh[2 * i]     = pack_hi2(kv4[i].x, kv4[i].y);
    pKh[2 * i + 1] = pack_hi2(kv4[i].z, kv4[i].w);
    pKl[2 * i]     = pack_hi2(kv4[i].x - hi_of(kv4[i].x), kv4[i].y - hi_of(kv4[i].y));
    pKl[2 * i + 1] = pack_hi2(kv4[i].z - hi_of(kv4[i].z), kv4[i].w - hi_of(kv4[i].w));
  }
  *(int4*)&Qhi[row][ci]     = *(int4*)&pQh[0];
  *(int4*)&Qhi[row][ci + 4] = *(int4*)&pQh[4];
  *(int4*)&Qlo[row][ci]     = *(int4*)&pQl[0];
  *(int4*)&Qlo[row][ci + 4] = *(int4*)&pQl[4];
  *(int4*)&Khi[row][ci]     = *(int4*)&pKh[0];
  *(int4*)&Khi[row][ci + 4] = *(int4*)&pKh[4];
  *(int4*)&Klo[row][ci]     = *(int4*)&pKl[0];
  *(int4*)&Klo[row][ci + 4] = *(int4*)&pKl[4];
  __syncthreads();
  floatx4 acc[2][2];
#pragma unroll
  for (int i = 0; i < 2; ++i)
#pragma unroll
    for (int j = 0; j < 2; ++j) acc[i][j] = (floatx4){0.f, 0.f, 0.f, 0.f};
#pragma unroll
  for (int kk = 0; kk < 64; kk += 32) {
    short8 ah[2], al[2], bhv[2], blv[2];
#pragma unroll
    for (int i = 0; i < 2; ++i) {
      ah[i]  = *(const short8*)&((const short*)Qhi[mw + i * 16 + l16])[kk + quad * 8];
      al[i]  = *(const short8*)&((const short*)Qlo[mw + i * 16 + l16])[kk + quad * 8];
      bhv[i] = *(const short8*)&((const short*)Khi[nw + i * 16 + l16])[kk + quad * 8];
      blv[i] = *(const short8*)&((const short*)Klo[nw + i * 16 + l16])[kk + quad * 8];
    }
#pragma unroll
    for (int i = 0; i < 2; ++i)
#pragma unroll
      for (int j = 0; j < 2; ++j) {
        acc[i][j] = __builtin_amdgcn_mfma_f32_16x16x32_bf16(ah[i], bhv[j], acc[i][j], 0, 0, 0);
        acc[i][j] = __builtin_amdgcn_mfma_f32_16x16x32_bf16(ah[i], blv[j], acc[i][j], 0, 0, 0);
        acc[i][j] = __builtin_amdgcn_mfma_f32_16x16x32_bf16(al[i], bhv[j], acc[i][j], 0, 0, 0);
      }
  }
#pragma unroll
  for (int i = 0; i < 2; ++i) {
    float rs_acc[4] = {0.f, 0.f, 0.f, 0.f};
#pragma unroll
    for (int r = 0; r < 4; ++r) {
      const int grow = i0 + mw + i * 16 + quad * 4 + r;
      const float qni = qn[(size_t)bh * 512 + grow];
      const float rq = 1.0f - qni;
#pragma unroll
      for (int j = 0; j < 2; ++j) {
        const int gcol = j0 + nw + j * 16 + l16;
        const float knj = kn[(size_t)bh * 512 + gcol];
        const float num = fmaxf(qni + knj - 2.0f * acc[i][j][r], 0.0f);
        const float den = fmaxf(rq * (1.0f - knj), EPS);
        const float wv = fmaf(2.0f * num, __builtin_amdgcn_rcpf(den), EPS);
        const float s_ = 1.0f + wv + sqrtf(wv * (wv + 2.0f));
        const float rr = __builtin_amdgcn_rcpf(s_);
        rs_acc[r] += rr;
        attn[((size_t)bh * 512 + grow) * 512 + gcol] = rr;
      }
    }
#pragma unroll
    for (int r = 0; r < 4; ++r) {
      float v = rs_acc[r];
      v += __shfl_xor(v, 1, 64); v += __shfl_xor(v, 2, 64);
      v += __shfl_xor(v, 4, 64); v += __shfl_xor(v, 8, 64);
      if (l16 == 0)
        atomicAdd(&rowsum[(size_t)bh * 512 + i0 + mw + i * 16 + quad * 4 + r], v);
    }
  }
}

// ---------- K6 v11: mobius scan, 8 lanes/row + one-step dot LOOKAHEAD ----------
__global__ __launch_bounds__(256) void k_scan(const float* __restrict__ V,
                                              const float* __restrict__ vn,
                                              const float* __restrict__ rw,
                                              const float* __restrict__ rowsum,
                                              float* __restrict__ att) {
  __shared__ __align__(16) float v_lds[64 * 64];
  __shared__ __align__(16) float swyn_lds[64 * 66];
  __shared__ float g_lds[64];
  const int blk = blockIdx.x;
  const int bh = blk >> 4;
  const int i0 = (blk & 15) * 32;
  const int t = threadIdx.x;
  const int lane = t & 63, w = t >> 6;
  const int row_blk = w * 8 + (lane >> 3);
  const int sub = lane & 7;
  const int d0 = sub * 8;
  const float* Vb = V + (size_t)bh * 512 * 64;
  const float* vnb = vn + (size_t)bh * 512;
  const float* arow = rw + ((size_t)bh * 512 + i0 + row_blk) * 512;
  const float inv_s = __builtin_amdgcn_rcpf(rowsum[(size_t)bh * 512 + i0 + row_blk]);

  float2v wsv[4];
#pragma unroll
  for (int k = 0; k < 4; ++k) wsv[k] = (float2v){0.f, 0.f};
  float xn = 0.0f;

  for (int jc = 0; jc < 512; jc += 64) {
#pragma unroll
    for (int it = 0; it < 4; ++it) {
      const int idx4 = it * 256 + t;
      *(float4*)&v_lds[idx4 * 4] = *(const float4*)&Vb[(size_t)jc * 64 + idx4 * 4];
    }
    const float4 a0 = *(const float4*)&arow[jc + sub * 8];
    const float4 a1 = *(const float4*)&arow[jc + sub * 8 + 4];
    const float4 n0 = *(const float4*)&vnb[jc + sub * 8];
    const float4 n1 = *(const float4*)&vnb[jc + sub * 8 + 4];
    const float wq[8] = {a0.x, a0.y, a0.z, a0.w, a1.x, a1.y, a1.z, a1.w};
    const float nq[8] = {n0.x, n0.y, n0.z, n0.w, n1.x, n1.y, n1.z, n1.w};
#pragma unroll
    for (int e = 0; e < 8; ++e) {
      const float wgt = wq[e] * inv_s;
      float2 p; p.x = wgt; p.y = (wgt * wgt) * nq[e];
      *(float2*)&swyn_lds[(sub * 8 + e) * 66 + row_blk * 2] = p;
    }
    __syncthreads();

    {
      const int jg = row_blk * 2;
      const float4 va0 = *(const float4*)&v_lds[jg * 64 + d0];
      const float4 va1 = *(const float4*)&v_lds[jg * 64 + d0 + 4];
      const float4 vb0 = *(const float4*)&v_lds[(jg + 1) * 64 + d0];
      const float4 vb1 = *(const float4*)&v_lds[(jg + 1) * 64 + d0 + 4];
      const float4 vc0 = *(const float4*)&v_lds[((jg + 2) & 63) * 64 + d0];
      const float4 vc1 = *(const float4*)&v_lds[((jg + 2) & 63) * 64 + d0 + 4];
      float p0 = va0.x * vb0.x + va0.y * vb0.y + va0.z * vb0.z + va0.w * vb0.w +
                 va1.x * vb1.x + va1.y * vb1.y + va1.z * vb1.z + va1.w * vb1.w;
      float p1 = vb0.x * vc0.x + vb0.y * vc0.y + vb0.z * vc0.z + vb0.w * vc0.w +
                 vb1.x * vc1.x + vb1.y * vc1.y + vb1.z * vc1.z + vb1.w * vc1.w;
      p0 += qperm<QP_XOR1>(p0); p0 += qperm<QP_XOR2>(p0); p0 += qperm<QP_HALFMIR>(p0);
      p1 += qperm<QP_XOR1>(p1); p1 += qperm<QP_XOR2>(p1); p1 += qperm<QP_HALFMIR>(p1);
      if (sub == 0) { g_lds[jg] = p0; g_lds[jg + 1] = p1; }
    }
    float2v vcur[4];
    {
      const float4 c0v = *(const float4*)&v_lds[d0];
      const float4 c1v = *(const float4*)&v_lds[d0 + 4];
      vcur[0] = (float2v){c0v.x, c0v.y}; vcur[1] = (float2v){c0v.z, c0v.w};
      vcur[2] = (float2v){c1v.x, c1v.y}; vcur[3] = (float2v){c1v.z, c1v.w};
    }
    float2v dd = wsv[0] * vcur[0];
    dd = fma2(wsv[1], vcur[1], dd);
    dd = fma2(wsv[2], vcur[2], dd);
    dd = fma2(wsv[3], vcur[3], dd);
    float D = dd.x + dd.y;
    D += qperm<QP_XOR1>(D); D += qperm<QP_XOR2>(D); D += qperm<QP_HALFMIR>(D);
    __syncthreads();

#pragma unroll
    for (int j = 0; j < 64; ++j) {
      const float2 sy2 = *(const float2*)&swyn_lds[j * 66 + row_blk * 2];
      const float sw = sy2.x, yn = sy2.y;
      const float xnyn1 = fmaf(xn, yn, 1.0f + EPS);
      const float sxy   = xn + yn;
      const float ynp1  = 1.0f + yn;
      const float Cfsw  = (1.0f - xn) * sw;
      float2v vnx[4];
      float E = 0.0f;
      if (j < 63) {
        const float4 nx0 = *(const float4*)&v_lds[(j + 1) * 64 + d0];
        const float4 nx1 = *(const float4*)&v_lds[(j + 1) * 64 + d0 + 4];
        vnx[0] = (float2v){nx0.x, nx0.y}; vnx[1] = (float2v){nx0.z, nx0.w};
        vnx[2] = (float2v){nx1.x, nx1.y}; vnx[3] = (float2v){nx1.z, nx1.w};
        float2v ee = wsv[0] * vnx[0];
        ee = fma2(wsv[1], vnx[1], ee);
        ee = fma2(wsv[2], vnx[2], ee);
        ee = fma2(wsv[3], vnx[3], ee);
        E = ee.x + ee.y;
        E += qperm<QP_XOR1>(E); E += qperm<QP_XOR2>(E); E += qperm<QP_HALFMIR>(E);
      }
      const float xy  = sw * D;
      const float den = fmaf(2.0f, xy, xnyn1);
      const float s2  = fmaf(2.0f, xy, sxy);
      const float Af  = fmaf(2.0f, xy, ynp1);
      const float id  = __builtin_amdgcn_rcpf(den);
      const float dn  = den - EPS;
      const float am  = Af * id;
      const float cm  = Cfsw * id;
      xn = (s2 * id) * (dn * id);
      const float2v amv = {am, am};
      const float2v cmv = {cm, cm};
      wsv[0] = fma2(amv, wsv[0], cmv * vcur[0]);
      wsv[1] = fma2(amv, wsv[1], cmv * vcur[1]);
      wsv[2] = fma2(amv, wsv[2], cmv * vcur[2]);
      wsv[3] = fma2(amv, wsv[3], cmv * vcur[3]);
      if (j < 63) {
        D = fmaf(am, E, cm * g_lds[j]);
        vcur[0] = vnx[0]; vcur[1] = vnx[1]; vcur[2] = vnx[2]; vcur[3] = vnx[3];
      }
    }
    __syncthreads();
  }
  const int b = bh >> 3, h = bh & 7;
  float* o = att + (((size_t)b * 512 + i0 + row_blk) * 512 + h * 64 + d0);
  float4 s0; s0.x = wsv[0].x; s0.y = wsv[0].y; s0.z = wsv[1].x; s0.w = wsv[1].y;
  float4 s1; s1.x = wsv[2].x; s1.y = wsv[2].y; s1.z = wsv[3].x; s1.w = wsv[3].y;
  *(float4*)&o[0] = s0;
  *(float4*)&o[4] = s1;
}

extern "C" void kernel_launch(void* const* d_in, const int* in_sizes, int n_in,
                              void* d_out, int out_size, void* d_ws, size_t ws_size,
                              hipStream_t stream) {
  const float* query = (const float*)d_in[0];
  const float* key_  = (const float*)d_in[1];
  const float* value = (const float*)d_in[2];
  const float* Wq = (const float*)d_in[3];
  const float* bq = (const float*)d_in[4];
  const float* Wk = (const float*)d_in[5];
  const float* bk = (const float*)d_in[6];
  const float* Wv = (const float*)d_in[7];
  const float* bv = (const float*)d_in[8];
  const float* Wo = (const float*)d_in[9];
  const float* bo = (const float*)d_in[10];
  float* ws = (float*)d_ws;
  const size_t M = 1u << 20;            // 1M floats
  float* Qb     = ws;                   // [32,512,64]
  float* Kb     = ws + 1 * M;
  float* Vb     = ws + 2 * M;
  float* qn     = ws + 3 * M;           // [32,512]
  float* kn     = qn + 16384;
  float* vn     = kn + 16384;
  float* rowsum = vn + 16384;           // [32,512]
  float* rw     = ws + 4 * M;           // [32,512,512] unnormalized weights
  float* t3     = ws + 12 * M;          // 3x [2048,512]
  float* att    = ws + 15 * M;          // [2048,512] row-major [B,S,E]
  float* to_    = ws + 16 * M;          // [2048,512]

  k_gemm_mfma<<<dim3(32, 8, 3), 256, 0, stream>>>(query, key_, value, Wq, Wk, Wv, t3);
  k_post<<<dim3(512, 3), 256, 0, stream>>>(t3, bq, bk, bv, Qb, Kb, Vb, qn, kn, vn,
                                           rowsum, 0);
  k_logits<<<dim3(8, 8, 32), 256, 0, stream>>>(Qb, Kb, qn, kn, rw, rowsum);
  k_scan<<<512, 256, 0, stream>>>(Vb, vn, rw, rowsum, att);
  k_gemm_mfma<<<dim3(32, 8, 1), 256, 0, stream>>>(att, att, att, Wo, Wo, Wo, to_);
  k_post<<<dim3(512, 1), 256, 0, stream>>>(to_, bo, bo, bo, (float*)d_out,
                                           nullptr, nullptr, nullptr, nullptr, nullptr,
                                           nullptr, 1);
}